// Round 9
// baseline (449.801 us; speedup 1.0000x reference)
//
#include <hip/hip_runtime.h>
#include <cmath>

// ---------------------------------------------------------------------------
// Round 9: store-free GEMM + candidate-based softmax.
// Attention is effectively one-hot: entries > CUT below the row max are
// < e^-28.6 -> write 0 (threshold 2e-2). So G is never materialized:
//  - GEMM (round-6 2-stage body, best measured 195us) epilogue for BOTH
//    halves is atomics-only: negatives -> per-row cosine max; modal ->
//    per-row dot-max + cosine-max + push cols within CUT of the running
//    atomic max (superset of true candidates: running max <= final max).
//  - resolve kernel: filter pushed set by stored fp32-acc dot (>= max-CUT),
//    recompute ~1.5 cols/row exactly in fp32, softmax over them, stream the
//    attention row as zeros+patches (coalesced float4), emit per-row outs.
//  - fallback for cnt>CAP (P~0 for Gaussian inputs): full exact row.
// Arena (packed bf16 chunks, 2KB/row) lives in the attention output region
// (dead before resolve writes rows). Candidate buffers in d_ws (~4.4 MB).
// ---------------------------------------------------------------------------

#define WAVE 64
#define CUT 2.0f
#define CAP 64

typedef __bf16 bf16x8_t __attribute__((ext_vector_type(8)));
typedef __bf16 bf16x4_t __attribute__((ext_vector_type(4)));
typedef float f32x4_t __attribute__((ext_vector_type(4)));

__device__ __forceinline__ float wave_reduce_sum(float v) {
#pragma unroll
    for (int o = 32; o > 0; o >>= 1) v += __shfl_down(v, o, WAVE);
    return v;
}
__device__ __forceinline__ float wave_reduce_max(float v) {
#pragma unroll
    for (int o = 32; o > 0; o >>= 1) v = fmaxf(v, __shfl_down(v, o, WAVE));
    return v;
}
__device__ __forceinline__ float wave_reduce_min(float v) {
#pragma unroll
    for (int o = 32; o > 0; o >>= 1) v = fminf(v, __shfl_down(v, o, WAVE));
    return v;
}

// monotone float <-> uint map for atomicMax on floats of any sign
__device__ __forceinline__ unsigned enc_f(float f) {
    unsigned u = __float_as_uint(f);
    return (u & 0x80000000u) ? ~u : (u | 0x80000000u);
}
__device__ __forceinline__ float dec_f(unsigned e) {
    unsigned u = (e & 0x80000000u) ? (e & 0x7fffffffu) : ~e;
    return __uint_as_float(u);
}

// ---------------- convert fp32 -> packed bf16 chunks + inverse norms -------
__global__ __launch_bounds__(256)
void convert_norms_kernel(const float* __restrict__ step,
                          const float* __restrict__ modal,
                          const float* __restrict__ negs,
                          char* __restrict__ arena,
                          float* __restrict__ ina, float* __restrict__ inb,
                          float* __restrict__ inn,
                          unsigned* __restrict__ negmax_u,
                          unsigned* __restrict__ dotmax_u,
                          unsigned* __restrict__ cosmax_u,
                          int* __restrict__ cnt, int N, int M) {
    const int tid = threadIdx.x, lane = tid & 63, wv = tid >> 6;
    const int b = blockIdx.x * 4 + wv;
    const float* src;
    if (b < N)          src = step  + (size_t)b * 1024;
    else if (b < N + M) src = modal + (size_t)(b - N) * 1024;
    else                src = negs  + (size_t)(b - N - M) * 1024;

    char* cb = arena + (size_t)b * 2048;
    float s = 0.0f;
#pragma unroll
    for (int q = 0; q < 4; q++) {
        const int idx = lane + q * 64;
        const float4 v = ((const float4*)src)[idx];
        bf16x4_t o;
        o[0] = (__bf16)v.x; o[1] = (__bf16)v.y;
        o[2] = (__bf16)v.z; o[3] = (__bf16)v.w;
        *(bf16x4_t*)(cb + (size_t)idx * 8) = o;
        s += v.x * v.x + v.y * v.y + v.z * v.z + v.w * v.w;
    }
    s = wave_reduce_sum(s);
    if (lane == 0) {
        const float inv = 1.0f / fmaxf(sqrtf(s), 1e-8f);
        if (b < N) {
            ina[b] = inv;
            negmax_u[b] = 0u; dotmax_u[b] = 0u; cosmax_u[b] = 0u; cnt[b] = 0;
        } else if (b < N + M) inb[b - N] = inv;
        else                  inn[b - N - M] = inv;
    }
}

// ---------------- store-free fused bf16 MFMA GEMM (round-6 body) -----------
#define GLD16(g, l)                                                       \
    __builtin_amdgcn_global_load_lds(                                     \
        (const __attribute__((address_space(1))) void*)(g),               \
        (__attribute__((address_space(3))) void*)(l), 16, 0, 0)

#define PIPE_BARRIER() asm volatile(                                      \
    "s_waitcnt vmcnt(0) lgkmcnt(0)\n\ts_barrier" ::: "memory")

__global__ __launch_bounds__(256, 2)
void gemm_fused_kernel(const char* __restrict__ arena, int N, int M,
                       const float* __restrict__ inv_nb,
                       const float* __restrict__ inv_nn,
                       unsigned* __restrict__ negmax_u,
                       unsigned* __restrict__ dotmax_u,
                       unsigned* __restrict__ cosmax_u,
                       int* __restrict__ cnt,
                       int* __restrict__ candcol,
                       float* __restrict__ canddot) {
    __shared__ __bf16 As[2][128 * 64];   // 2 x 16 KB
    __shared__ __bf16 Bs[2][128 * 64];   // 2 x 16 KB

    // supertile swizzle: 16 bm-blocks x 8 bn-blocks per supertile
    const int lin = blockIdx.x;            // 0..4095
    const int st  = lin >> 7;
    const int r128 = lin & 127;
    const int bxi = (st & 7) * 8 + (r128 & 7);
    const int byi = (st >> 3) * 16 + (r128 >> 3);
    const int bm = byi * 128, bn = bxi * 128;

    const int t = threadIdx.x, w = t >> 6, lane = t & 63;
    const int lane16 = lane & 15, lq = lane >> 4;
    const int wm = (w & 1) * 64, wn = (w >> 1) * 64;

    // staging: waves 0-1 -> As halves, waves 2-3 -> Bs halves
    // lds row = rowbase + r*8 + (lane>>3); lds octet = lane&7
    // global octet = (lane&7) ^ (lane>>3)   [xor swizzle]
    const int s_is_b  = w >> 1;
    const int rowbase = (w & 1) * 64;
    const int ln3 = lane >> 3;
    const int q_g = (lane & 7) ^ ln3;
    const int cbase = (s_is_b ? (N + bn) : bm) + rowbase;
    const char* gbase = arena + (size_t)(cbase + ln3) * 2048 + (size_t)q_g * 16;
    const int ldsoff = rowbase * 64;
    __bf16* ldsw0 = (s_is_b ? Bs[0] : As[0]) + ldsoff;
    __bf16* ldsw1 = (s_is_b ? Bs[1] : As[1]) + ldsoff;

    f32x4_t acc[4][4];
#pragma unroll
    for (int i = 0; i < 4; i++)
#pragma unroll
        for (int j = 0; j < 4; j++) acc[i][j] = (f32x4_t){0.f, 0.f, 0.f, 0.f};

    const int sxr = lane16 & 7;

    // prologue: tile 0 -> buffer 0
#pragma unroll
    for (int r = 0; r < 8; r++)
        GLD16(gbase + (size_t)r * 16384, ldsw0 + r * 512);

    for (int it = 0; it < 16; ++it) {
        PIPE_BARRIER();
        const int cur = it & 1;

        bf16x8_t af[2][4], bf[2][4];
#pragma unroll
        for (int kk = 0; kk < 2; kk++) {
            const int qo = ((lq + kk * 4) ^ sxr) * 8;
#pragma unroll
            for (int i = 0; i < 4; i++)
                af[kk][i] = *(const bf16x8_t*)&As[cur][(wm + i * 16 + lane16) * 64 + qo];
#pragma unroll
            for (int j = 0; j < 4; j++)
                bf[kk][j] = *(const bf16x8_t*)&Bs[cur][(wn + j * 16 + lane16) * 64 + qo];
        }

        if (it + 1 < 16) {
            const size_t k0b = (size_t)(it + 1) * 128;
            __bf16* ldsw = cur ? ldsw0 : ldsw1;
#pragma unroll
            for (int r = 0; r < 8; r++)
                GLD16(gbase + (size_t)r * 16384 + k0b, ldsw + r * 512);
        }

#pragma unroll
        for (int kk = 0; kk < 2; kk++)
#pragma unroll
            for (int i = 0; i < 4; i++)
#pragma unroll
                for (int j = 0; j < 4; j++)
                    acc[i][j] = __builtin_amdgcn_mfma_f32_16x16x32_bf16(
                        af[kk][i], bf[kk][j], acc[i][j], 0, 0, 0);
    }

    // C/D layout (16x16x32): col = lane16, row = lq*4 + reg
    if (bn < M) {
        // modal: per-row dot-max + cos-max atomics, push candidate cols
        float invnj[4];
#pragma unroll
        for (int j = 0; j < 4; j++)
            invnj[j] = inv_nb[bn + wn + j * 16 + lane16];
#pragma unroll
        for (int i = 0; i < 4; i++) {
#pragma unroll
            for (int r = 0; r < 4; r++) {
                const int row = bm + wm + i * 16 + lq * 4 + r;
                float d0 = acc[i][0][r], d1 = acc[i][1][r];
                float d2 = acc[i][2][r], d3 = acc[i][3][r];
                float dm = fmaxf(fmaxf(d0, d1), fmaxf(d2, d3));
                float cm = fmaxf(fmaxf(d0 * invnj[0], d1 * invnj[1]),
                                 fmaxf(d2 * invnj[2], d3 * invnj[3]));
#pragma unroll
                for (int o = 8; o > 0; o >>= 1) {
                    dm = fmaxf(dm, __shfl_xor(dm, o, WAVE));
                    cm = fmaxf(cm, __shfl_xor(cm, o, WAVE));
                }
                unsigned old = 0u;
                if (lane16 == 0) {
                    old = atomicMax(&dotmax_u[row], enc_f(dm));
                    atomicMax(&cosmax_u[row], enc_f(cm));
                }
                old = __shfl(old, lane & 48, WAVE);
                const float thr = fmaxf(dec_f(old), dm) - CUT;
                float dj[4] = {d0, d1, d2, d3};
#pragma unroll
                for (int j = 0; j < 4; j++) {
                    if (dj[j] >= thr) {
                        const int pos = atomicAdd(&cnt[row], 1);
                        if (pos < CAP) {
                            candcol[row * CAP + pos] = bn + wn + j * 16 + lane16;
                            canddot[row * CAP + pos] = dj[j];
                        }
                    }
                }
            }
        }
    } else {
        // negatives: per-row cosine max
        float invn[4];
#pragma unroll
        for (int j = 0; j < 4; j++)
            invn[j] = inv_nn[(bn - M) + wn + j * 16 + lane16];
#pragma unroll
        for (int i = 0; i < 4; i++) {
#pragma unroll
            for (int r = 0; r < 4; r++) {
                float v = acc[i][0][r] * invn[0];
                v = fmaxf(v, acc[i][1][r] * invn[1]);
                v = fmaxf(v, acc[i][2][r] * invn[2]);
                v = fmaxf(v, acc[i][3][r] * invn[3]);
#pragma unroll
                for (int o = 8; o > 0; o >>= 1)
                    v = fmaxf(v, __shfl_xor(v, o, WAVE));
                if (lane16 == 0)
                    atomicMax(&negmax_u[bm + wm + i * 16 + lq * 4 + r], enc_f(v));
            }
        }
    }
}

// ---------------- resolve: candidates -> exact softmax -> attn row ---------
__global__ __launch_bounds__(256)
void resolve_kernel(const float* __restrict__ step, const float* __restrict__ modal,
                    const float* __restrict__ ina, const float* __restrict__ inb,
                    const unsigned* __restrict__ cosmax_u,
                    const int* __restrict__ cnt,
                    const int* __restrict__ candcol,
                    const float* __restrict__ canddot,
                    float* __restrict__ perstep, float* __restrict__ wsum,
                    float* __restrict__ attn) {
    const int row = blockIdx.x, tid = threadIdx.x;
    const int lane = tid & 63, wv = tid >> 6;

    __shared__ float srow[1024];
    __shared__ float dots[4096];      // fallback only
    __shared__ int   lcol[CAP];
    __shared__ float ldot[CAP];
    __shared__ int   flist[16];
    __shared__ float fattn[16];
    __shared__ float fexact[16];
    __shared__ int   fn_s;
    __shared__ float red8[8];
    __shared__ float sc[2];

    ((float4*)srow)[tid] = ((const float4*)(step + (size_t)row * 1024))[tid];

    const int rawcnt = cnt[row];
    const int nc = min(rawcnt, CAP);
    if (tid < nc) {
        lcol[tid] = candcol[row * CAP + tid];
        ldot[tid] = canddot[row * CAP + tid];
    }
    __syncthreads();

    const float invT = 1.0f / 0.07f;
    float* arow = attn + (size_t)row * 4096;

    if (rawcnt <= CAP) {
        // filter pushed set by stored fp32-acc dot
        if (tid == 0) {
            float m0 = -3.4e38f; int am = 0;
            for (int i = 0; i < nc; i++)
                if (ldot[i] > m0) { m0 = ldot[i]; am = i; }
            int fn = 0;
            flist[fn++] = lcol[am];
            const float thr = m0 - CUT;
            for (int i = 0; i < nc && fn < 16; i++)
                if (i != am && ldot[i] >= thr) flist[fn++] = lcol[i];
            fn_s = fn;
        }
        __syncthreads();
        const int fn = fn_s;

        // exact fp32 dots, one candidate per wave
        for (int i = wv; i < fn; i += 4) {
            const float* mrow = modal + (size_t)flist[i] * 1024;
            float p = 0.0f;
#pragma unroll
            for (int q = 0; q < 16; q++) {
                const int idx = lane + q * 64;
                p = fmaf(srow[idx], mrow[idx], p);
            }
            p = wave_reduce_sum(p);
            if (lane == 0) fexact[i] = p;
        }
        __syncthreads();

        if (tid == 0) {
            float m = -3.4e38f;
            for (int i = 0; i < fn; i++) m = fmaxf(m, fexact[i]);
            float Z = 0.0f;
            for (int i = 0; i < fn; i++) Z += __expf((fexact[i] - m) * invT);
            const float invZ = 1.0f / Z;
            float wacc = 0.0f;
            for (int i = 0; i < fn; i++) {
                const float a = __expf((fexact[i] - m) * invT) * invZ;
                fattn[i] = a;
                wacc += a * fexact[i] * inb[flist[i]];
            }
            const float ia = ina[row];
            wsum[row] = wacc * ia;
            perstep[row] = dec_f(cosmax_u[row]) * ia;
        }
        __syncthreads();

        // stream the attention row: zeros + candidate patches
#pragma unroll
        for (int g = 0; g < 4; g++) {
            const int c0 = g * 1024 + tid * 4;
            float4 o = {0.f, 0.f, 0.f, 0.f};
            for (int i = 0; i < fn; i++) {
                const int d = flist[i] - c0;
                if ((unsigned)d < 4u) ((float*)&o)[d] = fattn[i];
            }
            *(float4*)(arow + c0) = o;
        }
    } else {
        // fallback (cnt overflow, P~0): full exact row
        for (int c = tid; c < 4096; c += 256) {
            const float* mrow = modal + (size_t)c * 1024;
            float p = 0.0f;
            for (int k = 0; k < 1024; k++) p = fmaf(srow[k], mrow[k], p);
            dots[c] = p;
        }
        __syncthreads();
        float m = -3.4e38f;
        for (int c = tid; c < 4096; c += 256) m = fmaxf(m, dots[c]);
        m = wave_reduce_max(m);
        if (lane == 0) red8[wv] = m;
        __syncthreads();
        if (tid == 0) sc[0] = fmaxf(fmaxf(red8[0], red8[1]), fmaxf(red8[2], red8[3]));
        __syncthreads();
        m = sc[0];
        float Zp = 0.0f;
        for (int c = tid; c < 4096; c += 256) Zp += __expf((dots[c] - m) * invT);
        Zp = wave_reduce_sum(Zp);
        __syncthreads();
        if (lane == 0) red8[wv] = Zp;
        __syncthreads();
        if (tid == 0) sc[1] = red8[0] + red8[1] + red8[2] + red8[3];
        __syncthreads();
        const float invZ = 1.0f / sc[1];
        float wacc = 0.0f;
        for (int c = tid; c < 4096; c += 256) {
            const float a = __expf((dots[c] - m) * invT) * invZ;
            arow[c] = a;
            wacc += a * dots[c] * inb[c];
        }
        wacc = wave_reduce_sum(wacc);
        __syncthreads();
        if (lane == 0) red8[wv] = wacc;
        __syncthreads();
        if (tid == 0) {
            const float ia = ina[row];
            wsum[row] = (red8[0] + red8[1] + red8[2] + red8[3]) * ia;
            perstep[row] = dec_f(cosmax_u[row]) * ia;
        }
    }
}

// ---------------- finalize scalars -----------------------------------------
__global__ __launch_bounds__(1024)
void finalize_kernel(const float* __restrict__ perstep, const float* __restrict__ w,
                     const unsigned* __restrict__ negmax_u,
                     const float* __restrict__ ina, float* __restrict__ out,
                     int N, size_t NM) {
    float s_a = 0.0f, s_w = 0.0f, s_n = 0.0f, mn = 3.4e38f;
    for (int i = threadIdx.x; i < N; i += 1024) {
        const float p = perstep[i];
        s_a += p;
        s_w += w[i];
        s_n += dec_f(negmax_u[i]) * ina[i];
        mn = fminf(mn, p);
    }
    s_a = wave_reduce_sum(s_a);
    s_w = wave_reduce_sum(s_w);
    s_n = wave_reduce_sum(s_n);
    mn  = wave_reduce_min(mn);
    __shared__ float ra[16], rw[16], rn[16], rm[16];
    const int lane = threadIdx.x & 63, wv = threadIdx.x >> 6;
    if (lane == 0) { ra[wv] = s_a; rw[wv] = s_w; rn[wv] = s_n; rm[wv] = mn; }
    __syncthreads();
    if (threadIdx.x == 0) {
        float ta = 0, tw = 0, tn = 0, tm = 3.4e38f;
#pragma unroll
        for (int i = 0; i < 16; i++) {
            ta += ra[i]; tw += rw[i]; tn += rn[i]; tm = fminf(tm, rm[i]);
        }
        const float inv = 1.0f / (float)N;
        const float alignment = ta * inv;
        const float weighted  = tw * inv;
        const float neg       = tn * inv;
        const float contrast  = alignment - neg;
        const float margin    = fmaxf(contrast - 0.2f, 0.0f);
        const float overall   = 0.7f * weighted + 0.3f * contrast;
        out[0] = alignment;
        out[1] = weighted;
        float* p = out + 2 + NM;
        p[0] = contrast;
        p[1] = margin;
        p[2] = alignment;   // positive_alignment
        p[3] = neg;
        p[4 + N] = tm;      // min_step_coherence
        p[5 + N] = overall;
    }
}

// ---------------------------------------------------------------------------
extern "C" void kernel_launch(void* const* d_in, const int* in_sizes, int n_in,
                              void* d_out, int out_size, void* d_ws, size_t ws_size,
                              hipStream_t stream) {
    const float* step  = (const float*)d_in[0];
    const float* modal = (const float*)d_in[1];
    const float* negs  = (const float*)d_in[2];
    float* out = (float*)d_out;

    const int K = 1024;
    const int N = in_sizes[0] / K;   // 8192
    const int M = in_sizes[1] / K;   // 4096
    const size_t NM = (size_t)N * (size_t)M;

    // ws layout
    float*    ina      = (float*)d_ws;                 // N
    float*    inb      = ina + N;                      // M
    float*    inn      = inb + M;                      // M
    unsigned* negmax_u = (unsigned*)(inn + M);         // N
    unsigned* dotmax_u = negmax_u + N;                 // N
    unsigned* cosmax_u = dotmax_u + N;                 // N
    int*      cnt      = (int*)(cosmax_u + N);         // N
    float*    wsum     = (float*)(cnt + N);            // N
    int*      candcol  = (int*)(wsum + N);             // N*CAP
    float*    canddot  = (float*)(candcol + (size_t)N * CAP); // N*CAP

    char* arena    = (char*)d_out + 16;   // packed bf16 chunks, 2KB each
    float* attn    = out + 2;
    float* perstep = out + 2 + NM + 4;

    // 1. convert inputs + inverse norms + init atomics
    convert_norms_kernel<<<(N + 2 * M) / 4, 256, 0, stream>>>(
        step, modal, negs, arena, ina, inb, inn,
        negmax_u, dotmax_u, cosmax_u, cnt, N, M);

    // 2. store-free fused GEMM (supertile-swizzled 1-D grid)
    const int nblocks = (N / 128) * ((2 * M) / 128);
    gemm_fused_kernel<<<nblocks, 256, 0, stream>>>(
        arena, N, M, inb, inn, negmax_u, dotmax_u, cosmax_u,
        cnt, candcol, canddot);

    // 3. resolve candidates -> exact softmax -> stream attention rows
    resolve_kernel<<<N, 256, 0, stream>>>(
        step, modal, ina, inb, cosmax_u, cnt, candcol, canddot,
        perstep, wsum, attn);

    // 4. scalars
    finalize_kernel<<<1, 1024, 0, stream>>>(perstep, wsum, negmax_u, ina, out, N, NM);
}

// Round 10
// 449.536 us; speedup vs baseline: 1.0006x; 1.0006x over previous
//
#include <hip/hip_runtime.h>
#include <cmath>

// ---------------------------------------------------------------------------
// Round 10: round-9 no-store structure + fire-and-forget epilogue atomics.
// GEMM = round-6 2-stage body (best measured). Modal epilogue: atomicMax
// (no return read), then a plain stale read of dotmax_u[row] for pruning —
// stale value is a lower bound of the final max, fmaxf(read, local dm)
// covers own contribution, so pushed set remains a superset of the true
// candidate set. Resolve recomputes candidates exactly in fp32.
// Arena (packed bf16 rows, 2KB each) in the attention output region.
// ---------------------------------------------------------------------------

#define WAVE 64
#define CUT 2.0f
#define CAP 64

typedef __bf16 bf16x8_t __attribute__((ext_vector_type(8)));
typedef __bf16 bf16x4_t __attribute__((ext_vector_type(4)));
typedef float f32x4_t __attribute__((ext_vector_type(4)));

__device__ __forceinline__ float wave_reduce_sum(float v) {
#pragma unroll
    for (int o = 32; o > 0; o >>= 1) v += __shfl_down(v, o, WAVE);
    return v;
}
__device__ __forceinline__ float wave_reduce_max(float v) {
#pragma unroll
    for (int o = 32; o > 0; o >>= 1) v = fmaxf(v, __shfl_down(v, o, WAVE));
    return v;
}
__device__ __forceinline__ float wave_reduce_min(float v) {
#pragma unroll
    for (int o = 32; o > 0; o >>= 1) v = fminf(v, __shfl_down(v, o, WAVE));
    return v;
}

// monotone float <-> uint map for atomicMax on floats of any sign
__device__ __forceinline__ unsigned enc_f(float f) {
    unsigned u = __float_as_uint(f);
    return (u & 0x80000000u) ? ~u : (u | 0x80000000u);
}
__device__ __forceinline__ float dec_f(unsigned e) {
    unsigned u = (e & 0x80000000u) ? (e & 0x7fffffffu) : ~e;
    return __uint_as_float(u);
}

// ---------------- convert fp32 -> packed bf16 chunks + inverse norms -------
__global__ __launch_bounds__(256)
void convert_norms_kernel(const float* __restrict__ step,
                          const float* __restrict__ modal,
                          const float* __restrict__ negs,
                          char* __restrict__ arena,
                          float* __restrict__ ina, float* __restrict__ inb,
                          float* __restrict__ inn,
                          unsigned* __restrict__ negmax_u,
                          unsigned* __restrict__ dotmax_u,
                          unsigned* __restrict__ cosmax_u,
                          int* __restrict__ cnt, int N, int M) {
    const int tid = threadIdx.x, lane = tid & 63, wv = tid >> 6;
    const int b = blockIdx.x * 4 + wv;
    const float* src;
    if (b < N)          src = step  + (size_t)b * 1024;
    else if (b < N + M) src = modal + (size_t)(b - N) * 1024;
    else                src = negs  + (size_t)(b - N - M) * 1024;

    char* cb = arena + (size_t)b * 2048;
    float s = 0.0f;
#pragma unroll
    for (int q = 0; q < 4; q++) {
        const int idx = lane + q * 64;
        const float4 v = ((const float4*)src)[idx];
        bf16x4_t o;
        o[0] = (__bf16)v.x; o[1] = (__bf16)v.y;
        o[2] = (__bf16)v.z; o[3] = (__bf16)v.w;
        *(bf16x4_t*)(cb + (size_t)idx * 8) = o;
        s += v.x * v.x + v.y * v.y + v.z * v.z + v.w * v.w;
    }
    s = wave_reduce_sum(s);
    if (lane == 0) {
        const float inv = 1.0f / fmaxf(sqrtf(s), 1e-8f);
        if (b < N) {
            ina[b] = inv;
            negmax_u[b] = 0u; dotmax_u[b] = 0u; cosmax_u[b] = 0u; cnt[b] = 0;
        } else if (b < N + M) inb[b - N] = inv;
        else                  inn[b - N - M] = inv;
    }
}

// ---------------- store-free fused bf16 MFMA GEMM (round-6 body) -----------
#define GLD16(g, l)                                                       \
    __builtin_amdgcn_global_load_lds(                                     \
        (const __attribute__((address_space(1))) void*)(g),               \
        (__attribute__((address_space(3))) void*)(l), 16, 0, 0)

#define PIPE_BARRIER() asm volatile(                                      \
    "s_waitcnt vmcnt(0) lgkmcnt(0)\n\ts_barrier" ::: "memory")

__global__ __launch_bounds__(256, 2)
void gemm_fused_kernel(const char* __restrict__ arena, int N, int M,
                       const float* __restrict__ inv_nb,
                       const float* __restrict__ inv_nn,
                       unsigned* __restrict__ negmax_u,
                       unsigned* __restrict__ dotmax_u,
                       unsigned* __restrict__ cosmax_u,
                       int* __restrict__ cnt,
                       int* __restrict__ candcol,
                       float* __restrict__ canddot) {
    __shared__ __bf16 As[2][128 * 64];   // 2 x 16 KB
    __shared__ __bf16 Bs[2][128 * 64];   // 2 x 16 KB

    // supertile swizzle: 16 bm-blocks x 8 bn-blocks per supertile
    const int lin = blockIdx.x;            // 0..4095
    const int st  = lin >> 7;
    const int r128 = lin & 127;
    const int bxi = (st & 7) * 8 + (r128 & 7);
    const int byi = (st >> 3) * 16 + (r128 >> 3);
    const int bm = byi * 128, bn = bxi * 128;

    const int t = threadIdx.x, w = t >> 6, lane = t & 63;
    const int lane16 = lane & 15, lq = lane >> 4;
    const int wm = (w & 1) * 64, wn = (w >> 1) * 64;

    // staging: waves 0-1 -> As halves, waves 2-3 -> Bs halves
    // lds row = rowbase + r*8 + (lane>>3); lds octet = lane&7
    // global octet = (lane&7) ^ (lane>>3)   [xor swizzle]
    const int s_is_b  = w >> 1;
    const int rowbase = (w & 1) * 64;
    const int ln3 = lane >> 3;
    const int q_g = (lane & 7) ^ ln3;
    const int cbase = (s_is_b ? (N + bn) : bm) + rowbase;
    const char* gbase = arena + (size_t)(cbase + ln3) * 2048 + (size_t)q_g * 16;
    const int ldsoff = rowbase * 64;
    __bf16* ldsw0 = (s_is_b ? Bs[0] : As[0]) + ldsoff;
    __bf16* ldsw1 = (s_is_b ? Bs[1] : As[1]) + ldsoff;

    f32x4_t acc[4][4];
#pragma unroll
    for (int i = 0; i < 4; i++)
#pragma unroll
        for (int j = 0; j < 4; j++) acc[i][j] = (f32x4_t){0.f, 0.f, 0.f, 0.f};

    const int sxr = lane16 & 7;

    // prologue: tile 0 -> buffer 0
#pragma unroll
    for (int r = 0; r < 8; r++)
        GLD16(gbase + (size_t)r * 16384, ldsw0 + r * 512);

    for (int it = 0; it < 16; ++it) {
        PIPE_BARRIER();
        const int cur = it & 1;

        bf16x8_t af[2][4], bf[2][4];
#pragma unroll
        for (int kk = 0; kk < 2; kk++) {
            const int qo = ((lq + kk * 4) ^ sxr) * 8;
#pragma unroll
            for (int i = 0; i < 4; i++)
                af[kk][i] = *(const bf16x8_t*)&As[cur][(wm + i * 16 + lane16) * 64 + qo];
#pragma unroll
            for (int j = 0; j < 4; j++)
                bf[kk][j] = *(const bf16x8_t*)&Bs[cur][(wn + j * 16 + lane16) * 64 + qo];
        }

        if (it + 1 < 16) {
            const size_t k0b = (size_t)(it + 1) * 128;
            __bf16* ldsw = cur ? ldsw0 : ldsw1;
#pragma unroll
            for (int r = 0; r < 8; r++)
                GLD16(gbase + (size_t)r * 16384 + k0b, ldsw + r * 512);
        }

#pragma unroll
        for (int kk = 0; kk < 2; kk++)
#pragma unroll
            for (int i = 0; i < 4; i++)
#pragma unroll
                for (int j = 0; j < 4; j++)
                    acc[i][j] = __builtin_amdgcn_mfma_f32_16x16x32_bf16(
                        af[kk][i], bf[kk][j], acc[i][j], 0, 0, 0);
    }

    // C/D layout (16x16x32): col = lane16, row = lq*4 + reg
    if (bn < M) {
        // modal: fire-and-forget per-row max atomics, then stale-read prune
        float invnj[4];
#pragma unroll
        for (int j = 0; j < 4; j++)
            invnj[j] = inv_nb[bn + wn + j * 16 + lane16];

        float dmv[4][4];
        // phase 1: reduce + fire-and-forget atomics (no result reads)
#pragma unroll
        for (int i = 0; i < 4; i++) {
#pragma unroll
            for (int r = 0; r < 4; r++) {
                const int row = bm + wm + i * 16 + lq * 4 + r;
                float dm = fmaxf(fmaxf(acc[i][0][r], acc[i][1][r]),
                                 fmaxf(acc[i][2][r], acc[i][3][r]));
                float cm = fmaxf(fmaxf(acc[i][0][r] * invnj[0],
                                       acc[i][1][r] * invnj[1]),
                                 fmaxf(acc[i][2][r] * invnj[2],
                                       acc[i][3][r] * invnj[3]));
#pragma unroll
                for (int o = 8; o > 0; o >>= 1) {
                    dm = fmaxf(dm, __shfl_xor(dm, o, WAVE));
                    cm = fmaxf(cm, __shfl_xor(cm, o, WAVE));
                }
                dmv[i][r] = dm;
                if (lane16 == 0) {
                    atomicMax(&dotmax_u[row], enc_f(dm));   // result unused
                    atomicMax(&cosmax_u[row], enc_f(cm));   // result unused
                }
            }
        }
        // phase 2: stale read of global max (lower bound of final) -> prune
#pragma unroll
        for (int i = 0; i < 4; i++) {
#pragma unroll
            for (int r = 0; r < 4; r++) {
                const int row = bm + wm + i * 16 + lq * 4 + r;
                const float g = dec_f(dotmax_u[row]);
                const float thr = fmaxf(g, dmv[i][r]) - CUT;
#pragma unroll
                for (int j = 0; j < 4; j++) {
                    const float dj = acc[i][j][r];
                    if (dj >= thr) {
                        const int pos = atomicAdd(&cnt[row], 1);
                        if (pos < CAP) {
                            candcol[row * CAP + pos] = bn + wn + j * 16 + lane16;
                            canddot[row * CAP + pos] = dj;
                        }
                    }
                }
            }
        }
    } else {
        // negatives: per-row cosine max (fire-and-forget)
        float invn[4];
#pragma unroll
        for (int j = 0; j < 4; j++)
            invn[j] = inv_nn[(bn - M) + wn + j * 16 + lane16];
#pragma unroll
        for (int i = 0; i < 4; i++) {
#pragma unroll
            for (int r = 0; r < 4; r++) {
                float v = acc[i][0][r] * invn[0];
                v = fmaxf(v, acc[i][1][r] * invn[1]);
                v = fmaxf(v, acc[i][2][r] * invn[2]);
                v = fmaxf(v, acc[i][3][r] * invn[3]);
#pragma unroll
                for (int o = 8; o > 0; o >>= 1)
                    v = fmaxf(v, __shfl_xor(v, o, WAVE));
                if (lane16 == 0)
                    atomicMax(&negmax_u[bm + wm + i * 16 + lq * 4 + r], enc_f(v));
            }
        }
    }
}

// ---------------- resolve: candidates -> exact softmax -> attn row ---------
__global__ __launch_bounds__(256)
void resolve_kernel(const float* __restrict__ step, const float* __restrict__ modal,
                    const float* __restrict__ ina, const float* __restrict__ inb,
                    const unsigned* __restrict__ cosmax_u,
                    const int* __restrict__ cnt,
                    const int* __restrict__ candcol,
                    const float* __restrict__ canddot,
                    float* __restrict__ perstep, float* __restrict__ wsum,
                    float* __restrict__ attn) {
    const int row = blockIdx.x, tid = threadIdx.x;
    const int lane = tid & 63, wv = tid >> 6;

    __shared__ float srow[1024];
    __shared__ float dots[4096];      // fallback only
    __shared__ int   lcol[CAP];
    __shared__ float ldot[CAP];
    __shared__ int   flist[16];
    __shared__ float fattn[16];
    __shared__ float fexact[16];
    __shared__ int   fn_s;
    __shared__ float red8[8];
    __shared__ float sc[2];

    ((float4*)srow)[tid] = ((const float4*)(step + (size_t)row * 1024))[tid];

    const int rawcnt = cnt[row];
    const int nc = min(rawcnt, CAP);
    if (tid < nc) {
        lcol[tid] = candcol[row * CAP + tid];
        ldot[tid] = canddot[row * CAP + tid];
    }
    __syncthreads();

    const float invT = 1.0f / 0.07f;
    float* arow = attn + (size_t)row * 4096;

    if (rawcnt <= CAP) {
        // filter pushed set by stored fp32-acc dot
        if (tid == 0) {
            float m0 = -3.4e38f; int am = 0;
            for (int i = 0; i < nc; i++)
                if (ldot[i] > m0) { m0 = ldot[i]; am = i; }
            int fn = 0;
            flist[fn++] = lcol[am];
            const float thr = m0 - CUT;
            for (int i = 0; i < nc && fn < 16; i++)
                if (i != am && ldot[i] >= thr) flist[fn++] = lcol[i];
            fn_s = fn;
        }
        __syncthreads();
        const int fn = fn_s;

        // exact fp32 dots, one candidate per wave
        for (int i = wv; i < fn; i += 4) {
            const float* mrow = modal + (size_t)flist[i] * 1024;
            float p = 0.0f;
#pragma unroll
            for (int q = 0; q < 16; q++) {
                const int idx = lane + q * 64;
                p = fmaf(srow[idx], mrow[idx], p);
            }
            p = wave_reduce_sum(p);
            if (lane == 0) fexact[i] = p;
        }
        __syncthreads();

        if (tid == 0) {
            float m = -3.4e38f;
            for (int i = 0; i < fn; i++) m = fmaxf(m, fexact[i]);
            float Z = 0.0f;
            for (int i = 0; i < fn; i++) Z += __expf((fexact[i] - m) * invT);
            const float invZ = 1.0f / Z;
            float wacc = 0.0f;
            for (int i = 0; i < fn; i++) {
                const float a = __expf((fexact[i] - m) * invT) * invZ;
                fattn[i] = a;
                wacc += a * fexact[i] * inb[flist[i]];
            }
            const float ia = ina[row];
            wsum[row] = wacc * ia;
            perstep[row] = dec_f(cosmax_u[row]) * ia;
        }
        __syncthreads();

        // stream the attention row: zeros + candidate patches
#pragma unroll
        for (int g = 0; g < 4; g++) {
            const int c0 = g * 1024 + tid * 4;
            float4 o = {0.f, 0.f, 0.f, 0.f};
            for (int i = 0; i < fn; i++) {
                const int d = flist[i] - c0;
                if ((unsigned)d < 4u) ((float*)&o)[d] = fattn[i];
            }
            *(float4*)(arow + c0) = o;
        }
    } else {
        // fallback (cnt overflow, P~0): full exact row
        for (int c = tid; c < 4096; c += 256) {
            const float* mrow = modal + (size_t)c * 1024;
            float p = 0.0f;
            for (int k = 0; k < 1024; k++) p = fmaf(srow[k], mrow[k], p);
            dots[c] = p;
        }
        __syncthreads();
        float m = -3.4e38f;
        for (int c = tid; c < 4096; c += 256) m = fmaxf(m, dots[c]);
        m = wave_reduce_max(m);
        if (lane == 0) red8[wv] = m;
        __syncthreads();
        if (tid == 0) sc[0] = fmaxf(fmaxf(red8[0], red8[1]), fmaxf(red8[2], red8[3]));
        __syncthreads();
        m = sc[0];
        float Zp = 0.0f;
        for (int c = tid; c < 4096; c += 256) Zp += __expf((dots[c] - m) * invT);
        Zp = wave_reduce_sum(Zp);
        __syncthreads();
        if (lane == 0) red8[wv] = Zp;
        __syncthreads();
        if (tid == 0) sc[1] = red8[0] + red8[1] + red8[2] + red8[3];
        __syncthreads();
        const float invZ = 1.0f / sc[1];
        float wacc = 0.0f;
        for (int c = tid; c < 4096; c += 256) {
            const float a = __expf((dots[c] - m) * invT) * invZ;
            arow[c] = a;
            wacc += a * dots[c] * inb[c];
        }
        wacc = wave_reduce_sum(wacc);
        __syncthreads();
        if (lane == 0) red8[wv] = wacc;
        __syncthreads();
        if (tid == 0) {
            const float ia = ina[row];
            wsum[row] = (red8[0] + red8[1] + red8[2] + red8[3]) * ia;
            perstep[row] = dec_f(cosmax_u[row]) * ia;
        }
    }
}

// ---------------- finalize scalars -----------------------------------------
__global__ __launch_bounds__(1024)
void finalize_kernel(const float* __restrict__ perstep, const float* __restrict__ w,
                     const unsigned* __restrict__ negmax_u,
                     const float* __restrict__ ina, float* __restrict__ out,
                     int N, size_t NM) {
    float s_a = 0.0f, s_w = 0.0f, s_n = 0.0f, mn = 3.4e38f;
    for (int i = threadIdx.x; i < N; i += 1024) {
        const float p = perstep[i];
        s_a += p;
        s_w += w[i];
        s_n += dec_f(negmax_u[i]) * ina[i];
        mn = fminf(mn, p);
    }
    s_a = wave_reduce_sum(s_a);
    s_w = wave_reduce_sum(s_w);
    s_n = wave_reduce_sum(s_n);
    mn  = wave_reduce_min(mn);
    __shared__ float ra[16], rw[16], rn[16], rm[16];
    const int lane = threadIdx.x & 63, wv = threadIdx.x >> 6;
    if (lane == 0) { ra[wv] = s_a; rw[wv] = s_w; rn[wv] = s_n; rm[wv] = mn; }
    __syncthreads();
    if (threadIdx.x == 0) {
        float ta = 0, tw = 0, tn = 0, tm = 3.4e38f;
#pragma unroll
        for (int i = 0; i < 16; i++) {
            ta += ra[i]; tw += rw[i]; tn += rn[i]; tm = fminf(tm, rm[i]);
        }
        const float inv = 1.0f / (float)N;
        const float alignment = ta * inv;
        const float weighted  = tw * inv;
        const float neg       = tn * inv;
        const float contrast  = alignment - neg;
        const float margin    = fmaxf(contrast - 0.2f, 0.0f);
        const float overall   = 0.7f * weighted + 0.3f * contrast;
        out[0] = alignment;
        out[1] = weighted;
        float* p = out + 2 + NM;
        p[0] = contrast;
        p[1] = margin;
        p[2] = alignment;   // positive_alignment
        p[3] = neg;
        p[4 + N] = tm;      // min_step_coherence
        p[5 + N] = overall;
    }
}

// ---------------------------------------------------------------------------
extern "C" void kernel_launch(void* const* d_in, const int* in_sizes, int n_in,
                              void* d_out, int out_size, void* d_ws, size_t ws_size,
                              hipStream_t stream) {
    const float* step  = (const float*)d_in[0];
    const float* modal = (const float*)d_in[1];
    const float* negs  = (const float*)d_in[2];
    float* out = (float*)d_out;

    const int K = 1024;
    const int N = in_sizes[0] / K;   // 8192
    const int M = in_sizes[1] / K;   // 4096
    const size_t NM = (size_t)N * (size_t)M;

    // ws layout
    float*    ina      = (float*)d_ws;                 // N
    float*    inb      = ina + N;                      // M
    float*    inn      = inb + M;                      // M
    unsigned* negmax_u = (unsigned*)(inn + M);         // N
    unsigned* dotmax_u = negmax_u + N;                 // N
    unsigned* cosmax_u = dotmax_u + N;                 // N
    int*      cnt      = (int*)(cosmax_u + N);         // N
    float*    wsum     = (float*)(cnt + N);            // N
    int*      candcol  = (int*)(wsum + N);             // N*CAP
    float*    canddot  = (float*)(candcol + (size_t)N * CAP); // N*CAP

    char* arena    = (char*)d_out + 16;   // packed bf16 rows, 2KB each
    float* attn    = out + 2;
    float* perstep = out + 2 + NM + 4;

    // 1. convert inputs + inverse norms + init atomics
    convert_norms_kernel<<<(N + 2 * M) / 4, 256, 0, stream>>>(
        step, modal, negs, arena, ina, inb, inn,
        negmax_u, dotmax_u, cosmax_u, cnt, N, M);

    // 2. store-free fused GEMM (supertile-swizzled 1-D grid)
    const int nblocks = (N / 128) * ((2 * M) / 128);
    gemm_fused_kernel<<<nblocks, 256, 0, stream>>>(
        arena, N, M, inb, inn, negmax_u, dotmax_u, cosmax_u,
        cnt, candcol, canddot);

    // 3. resolve candidates -> exact softmax -> stream attention rows
    resolve_kernel<<<N, 256, 0, stream>>>(
        step, modal, ina, inb, cosmax_u, cnt, candcol, canddot,
        perstep, wsum, attn);

    // 4. scalars
    finalize_kernel<<<1, 1024, 0, stream>>>(perstep, wsum, negmax_u, ina, out, N, NM);
}

// Round 11
// 382.990 us; speedup vs baseline: 1.1744x; 1.1738x over previous
//
#include <hip/hip_runtime.h>
#include <cmath>

// ---------------------------------------------------------------------------
// Round 11: round-6 design (best total, 398.9us) + two GEMM deltas:
//  (a) L2-resident supertile: 32 bm x 8 bn, bmi-fastest, so XCD x (lin%8)
//      owns bmi===x -> per-XCD working set = 4 A-panels (1MB) + 8 B-panels
//      (2MB) < 4MB L2, and consecutive supertiles reuse the same A panels.
//      (old 16x8 supertile refetched ~24MB/round from L3 -> 192MB FETCH.)
//  (b) next-tile global_load_lds issued right after the barrier, before
//      fragment reads (+~300cyc in flight; !cur buffer free per lgkmcnt(0)).
// Arena (inside attention output region): slot r (16 KB) =
//   [ G-bf16 row r : 8 KB | input bf16 chunks 4r..4r+3 : 8 KB ]
// chunk order: 0..N-1 step, N..N+M-1 modal, N+M..N+2M-1 negs.
// ---------------------------------------------------------------------------

#define WAVE 64

typedef __bf16 bf16x8_t __attribute__((ext_vector_type(8)));
typedef __bf16 bf16x4_t __attribute__((ext_vector_type(4)));
typedef float f32x4_t __attribute__((ext_vector_type(4)));

__device__ __forceinline__ float wave_reduce_sum(float v) {
#pragma unroll
    for (int o = 32; o > 0; o >>= 1) v += __shfl_down(v, o, WAVE);
    return v;
}
__device__ __forceinline__ float wave_reduce_max(float v) {
#pragma unroll
    for (int o = 32; o > 0; o >>= 1) v = fmaxf(v, __shfl_down(v, o, WAVE));
    return v;
}
__device__ __forceinline__ float wave_reduce_min(float v) {
#pragma unroll
    for (int o = 32; o > 0; o >>= 1) v = fminf(v, __shfl_down(v, o, WAVE));
    return v;
}

// monotone float <-> uint map for atomicMax on floats of any sign
__device__ __forceinline__ unsigned enc_f(float f) {
    unsigned u = __float_as_uint(f);
    return (u & 0x80000000u) ? ~u : (u | 0x80000000u);
}
__device__ __forceinline__ float dec_f(unsigned e) {
    unsigned u = (e & 0x80000000u) ? (e & 0x7fffffffu) : ~e;
    return __uint_as_float(u);
}

// ---------------- convert fp32 -> bf16 chunks + inverse norms --------------
// one row per WAVE (4 rows/block), no block barriers.
__global__ __launch_bounds__(256)
void convert_norms_kernel(const float* __restrict__ step,
                          const float* __restrict__ modal,
                          const float* __restrict__ negs,
                          char* __restrict__ arena,
                          float* __restrict__ ina, float* __restrict__ inb,
                          float* __restrict__ inn,
                          unsigned* __restrict__ negmax_u, int N, int M) {
    const int tid = threadIdx.x, lane = tid & 63, wv = tid >> 6;
    const int b = blockIdx.x * 4 + wv;
    const float* src;
    if (b < N)          src = step  + (size_t)b * 1024;
    else if (b < N + M) src = modal + (size_t)(b - N) * 1024;
    else                src = negs  + (size_t)(b - N - M) * 1024;

    char* cb = arena + (((size_t)(b >> 2)) << 14) + ((size_t)(b & 3) << 11) + 8192;
    float s = 0.0f;
#pragma unroll
    for (int q = 0; q < 4; q++) {
        const int idx = lane + q * 64;
        const float4 v = ((const float4*)src)[idx];
        bf16x4_t o;
        o[0] = (__bf16)v.x; o[1] = (__bf16)v.y;
        o[2] = (__bf16)v.z; o[3] = (__bf16)v.w;
        *(bf16x4_t*)(cb + (size_t)idx * 8) = o;
        s += v.x * v.x + v.y * v.y + v.z * v.z + v.w * v.w;
    }
    s = wave_reduce_sum(s);
    if (lane == 0) {
        const float inv = 1.0f / fmaxf(sqrtf(s), 1e-8f);
        if (b < N)          { ina[b] = inv; negmax_u[b] = 0u; }
        else if (b < N + M) inb[b - N] = inv;
        else                inn[b - N - M] = inv;
    }
}

// ---------------- fused bf16 MFMA GEMM over arena chunks -------------------
#define GLD16(g, l)                                                       \
    __builtin_amdgcn_global_load_lds(                                     \
        (const __attribute__((address_space(1))) void*)(g),               \
        (__attribute__((address_space(3))) void*)(l), 16, 0, 0)

#define PIPE_BARRIER() asm volatile(                                      \
    "s_waitcnt vmcnt(0) lgkmcnt(0)\n\ts_barrier" ::: "memory")

__global__ __launch_bounds__(256, 2)
void gemm_fused_kernel(char* __restrict__ arena, int N, int M,
                       const float* __restrict__ inv_nn,
                       unsigned* __restrict__ negmax_u) {
    __shared__ __bf16 As[2][128 * 64];   // 2 x 16 KB
    __shared__ __bf16 Bs[2][128 * 64];   // 2 x 16 KB

    // L2-resident supertile: 32 bm x 8 bn, bmi fastest (XCD = lin % 8)
    const int lin = blockIdx.x;
    const int nbn = (2 * M) >> 7;          // 64
    const int SBM = 32, SBN = 8, PER = SBM * SBN;   // 256
    const int sid = lin / PER;
    const int q   = lin % PER;
    const int bmi = q % SBM;
    const int bni = q / SBM;
    const int stn_per = nbn / SBN;         // 8
    const int bmg = sid / stn_per;
    const int stn = sid % stn_per;
    const int bm = (bmg * SBM + bmi) << 7;
    const int bn = (stn * SBN + bni) << 7;

    const int t = threadIdx.x, w = t >> 6, lane = t & 63;
    const int lane16 = lane & 15, lq = lane >> 4;
    const int wm = (w & 1) * 64, wn = (w >> 1) * 64;

    // staging: waves 0-1 -> As halves, waves 2-3 -> Bs halves
    // lds row = rowbase + r*8 + (lane>>3); lds octet = lane&7
    // global octet = (lane&7) ^ (lane>>3)   [xor swizzle]
    const int s_is_b  = w >> 1;
    const int rowbase = (w & 1) * 64;
    const int ln3 = lane >> 3;
    const int q_g = (lane & 7) ^ ln3;
    const int cbase = (s_is_b ? (N + bn) : bm) + rowbase;
    const int cc = cbase + ln3;
    const size_t off0 = (((size_t)(cc >> 2)) << 14) +
                        ((size_t)(cc & 3) << 11) + 8192 + (size_t)q_g * 16;
    const char* gbase = arena + off0;
    const int ldsoff = rowbase * 64;
    __bf16* ldsw0 = (s_is_b ? Bs[0] : As[0]) + ldsoff;
    __bf16* ldsw1 = (s_is_b ? Bs[1] : As[1]) + ldsoff;

    f32x4_t acc[4][4];
#pragma unroll
    for (int i = 0; i < 4; i++)
#pragma unroll
        for (int j = 0; j < 4; j++) acc[i][j] = (f32x4_t){0.f, 0.f, 0.f, 0.f};

    const int sxr = lane16 & 7;

    // prologue: tile 0 -> buffer 0
#pragma unroll
    for (int r = 0; r < 8; r++)
        GLD16(gbase + (size_t)r * 32768, ldsw0 + r * 512);

    for (int it = 0; it < 16; ++it) {
        PIPE_BARRIER();          // my prev loads landed + everyone's reads done
        const int cur = it & 1;

        // issue next tile's loads FIRST (into !cur, proven free by barrier);
        // they stay in flight across frag reads + MFMA phase
        if (it + 1 < 16) {
            const size_t k0b = (size_t)(it + 1) * 128;
            __bf16* ldsw = cur ? ldsw0 : ldsw1;
#pragma unroll
            for (int r = 0; r < 8; r++)
                GLD16(gbase + (size_t)r * 32768 + k0b, ldsw + r * 512);
        }

        bf16x8_t af[2][4], bf[2][4];
#pragma unroll
        for (int kk = 0; kk < 2; kk++) {
            const int qo = ((lq + kk * 4) ^ sxr) * 8;
#pragma unroll
            for (int i = 0; i < 4; i++)
                af[kk][i] = *(const bf16x8_t*)&As[cur][(wm + i * 16 + lane16) * 64 + qo];
#pragma unroll
            for (int j = 0; j < 4; j++)
                bf[kk][j] = *(const bf16x8_t*)&Bs[cur][(wn + j * 16 + lane16) * 64 + qo];
        }

#pragma unroll
        for (int kk = 0; kk < 2; kk++)
#pragma unroll
            for (int i = 0; i < 4; i++)
#pragma unroll
                for (int j = 0; j < 4; j++)
                    acc[i][j] = __builtin_amdgcn_mfma_f32_16x16x32_bf16(
                        af[kk][i], bf[kk][j], acc[i][j], 0, 0, 0);
    }

    // C/D layout (16x16x32): col = lane16, row = lq*4 + reg
    if (bn < M) {
        // modal half: store G as bf16 into slot front halves
#pragma unroll
        for (int i = 0; i < 4; i++) {
#pragma unroll
            for (int r = 0; r < 4; r++) {
                const int grow = bm + wm + i * 16 + lq * 4 + r;
                __bf16* dst = (__bf16*)(arena + ((size_t)grow << 14)) +
                              bn + wn + lane16;
#pragma unroll
                for (int j = 0; j < 4; j++)
                    dst[j * 16] = (__bf16)acc[i][j][r];
            }
        }
    } else {
        // negatives half: per-row cosine max via atomicMax
        float invn[4];
#pragma unroll
        for (int j = 0; j < 4; j++)
            invn[j] = inv_nn[(bn - M) + wn + j * 16 + lane16];
#pragma unroll
        for (int i = 0; i < 4; i++) {
#pragma unroll
            for (int r = 0; r < 4; r++) {
                float v = acc[i][0][r] * invn[0];
                v = fmaxf(v, acc[i][1][r] * invn[1]);
                v = fmaxf(v, acc[i][2][r] * invn[2]);
                v = fmaxf(v, acc[i][3][r] * invn[3]);
#pragma unroll
                for (int o = 8; o > 0; o >>= 1)
                    v = fmaxf(v, __shfl_xor(v, o, WAVE));
                if (lane16 == 0)
                    atomicMax(&negmax_u[bm + wm + i * 16 + lq * 4 + r], enc_f(v));
            }
        }
    }
}

// ---------------- softmax with fp32 fix-up, coalesced layout ---------------
#define CUT 2.0f
#define MAXCAND 64

__global__ __launch_bounds__(256)
void softmax_fix_kernel(char* __restrict__ arena, const float* __restrict__ step,
                        const float* __restrict__ modal,
                        const float* __restrict__ ina, const float* __restrict__ inb,
                        float* __restrict__ perstep, float* __restrict__ wout,
                        float* __restrict__ attn) {
    const int row = blockIdx.x, tid = threadIdx.x;
    const int lane = tid & 63, wv = tid >> 6;

    __shared__ float srow_s[1024];
    __shared__ float red[8];
    __shared__ float bcast[2];
    __shared__ int   cand[MAXCAND];
    __shared__ float exact[MAXCAND];
    __shared__ int   cnt;

    if (tid == 0) cnt = 0;
    ((float4*)srow_s)[tid] = ((const float4*)(step + (size_t)row * 1024))[tid];

    const __bf16* gb = (const __bf16*)(arena + ((size_t)row << 14));
    float vals[16];
    float invn[16];
#pragma unroll
    for (int g = 0; g < 4; g++) {
        const bf16x4_t v = *(const bf16x4_t*)(gb + g * 1024 + tid * 4);
        const float4 x = *(const float4*)(inb + g * 1024 + tid * 4);
        vals[g * 4 + 0] = (float)v[0]; vals[g * 4 + 1] = (float)v[1];
        vals[g * 4 + 2] = (float)v[2]; vals[g * 4 + 3] = (float)v[3];
        invn[g * 4 + 0] = x.x; invn[g * 4 + 1] = x.y;
        invn[g * 4 + 2] = x.z; invn[g * 4 + 3] = x.w;
    }

    float dmax = -3.4e38f;
#pragma unroll
    for (int j = 0; j < 16; j++) dmax = fmaxf(dmax, vals[j]);
    float wm = wave_reduce_max(dmax);
    if (lane == 0) red[wv] = wm;
    __syncthreads();   // also covers cnt=0 and srow_s
    if (tid == 0) bcast[0] = fmaxf(fmaxf(red[0], red[1]), fmaxf(red[2], red[3]));
    __syncthreads();
    const float m0 = bcast[0];

    const float thr = m0 - CUT;
#pragma unroll
    for (int g = 0; g < 4; g++)
#pragma unroll
        for (int u = 0; u < 4; u++) {
            if (vals[g * 4 + u] >= thr) {
                const int pos = atomicAdd(&cnt, 1);
                if (pos < MAXCAND) cand[pos] = g * 1024 + tid * 4 + u;
            }
        }
    __syncthreads();
    const int nc = min(cnt, MAXCAND);

    // exact fp32 dots, one candidate per wave
    for (int i = wv; i < nc; i += 4) {
        const float* mrow = modal + (size_t)cand[i] * 1024;
        float p = 0.0f;
#pragma unroll
        for (int q = 0; q < 16; q++) {
            const int idx = lane + q * 64;
            p = fmaf(srow_s[idx], mrow[idx], p);
        }
        p = wave_reduce_sum(p);
        if (lane == 0) exact[i] = p;
    }
    __syncthreads();

    for (int i = 0; i < nc; i++) {
        const int c = cand[i];
        if (((c & 1023) >> 2) == tid) vals[(c >> 10) * 4 + (c & 3)] = exact[i];
    }

    float dmax2 = -3.4e38f, cmax = -3.4e38f;
#pragma unroll
    for (int j = 0; j < 16; j++) {
        dmax2 = fmaxf(dmax2, vals[j]);
        cmax = fmaxf(cmax, vals[j] * invn[j]);
    }
    float wg = wave_reduce_max(dmax2);
    float wc = wave_reduce_max(cmax);
    if (lane == 0) { red[wv] = wg; red[4 + wv] = wc; }
    __syncthreads();
    if (tid == 0) {
        bcast[0] = fmaxf(fmaxf(red[0], red[1]), fmaxf(red[2], red[3]));
        bcast[1] = fmaxf(fmaxf(red[4], red[5]), fmaxf(red[6], red[7]));
    }
    __syncthreads();
    const float invT = 1.0f / 0.07f;
    const float mlog = bcast[0] * invT;
    const float cmaxAll = bcast[1];

    float evals[16];
    float lsum = 0.0f;
#pragma unroll
    for (int j = 0; j < 16; j++) {
        const float e = __expf(vals[j] * invT - mlog);
        evals[j] = e;
        lsum += e;
    }
    lsum = wave_reduce_sum(lsum);
    __syncthreads();
    if (lane == 0) red[wv] = lsum;
    __syncthreads();
    if (tid == 0) bcast[0] = red[0] + red[1] + red[2] + red[3];
    __syncthreads();
    const float invZ = 1.0f / bcast[0];

    float* arow = attn + (size_t)row * 4096;
    float wacc = 0.0f;
#pragma unroll
    for (int g = 0; g < 4; g++) {
        float4 o;
        const float a0 = evals[g * 4 + 0] * invZ, a1 = evals[g * 4 + 1] * invZ;
        const float a2 = evals[g * 4 + 2] * invZ, a3 = evals[g * 4 + 3] * invZ;
        o.x = a0; o.y = a1; o.z = a2; o.w = a3;
        *(float4*)(arow + g * 1024 + tid * 4) = o;
        wacc += a0 * vals[g * 4 + 0] * invn[g * 4 + 0];
        wacc += a1 * vals[g * 4 + 1] * invn[g * 4 + 1];
        wacc += a2 * vals[g * 4 + 2] * invn[g * 4 + 2];
        wacc += a3 * vals[g * 4 + 3] * invn[g * 4 + 3];
    }
    wacc = wave_reduce_sum(wacc);
    __syncthreads();
    if (lane == 0) red[wv] = wacc;
    __syncthreads();
    if (tid == 0) {
        const float inv_na = ina[row];
        perstep[row] = cmaxAll * inv_na;
        wout[row] = (red[0] + red[1] + red[2] + red[3]) * inv_na;
    }
}

// ---------------- finalize scalars -----------------------------------------
__global__ __launch_bounds__(1024)
void finalize_kernel(const float* __restrict__ perstep, const float* __restrict__ w,
                     const unsigned* __restrict__ negmax_u,
                     const float* __restrict__ ina, float* __restrict__ out,
                     int N, size_t NM) {
    float s_a = 0.0f, s_w = 0.0f, s_n = 0.0f, mn = 3.4e38f;
    for (int i = threadIdx.x; i < N; i += 1024) {
        const float p = perstep[i];
        s_a += p;
        s_w += w[i];
        s_n += dec_f(negmax_u[i]) * ina[i];
        mn = fminf(mn, p);
    }
    s_a = wave_reduce_sum(s_a);
    s_w = wave_reduce_sum(s_w);
    s_n = wave_reduce_sum(s_n);
    mn  = wave_reduce_min(mn);
    __shared__ float ra[16], rw[16], rn[16], rm[16];
    const int lane = threadIdx.x & 63, wv = threadIdx.x >> 6;
    if (lane == 0) { ra[wv] = s_a; rw[wv] = s_w; rn[wv] = s_n; rm[wv] = mn; }
    __syncthreads();
    if (threadIdx.x == 0) {
        float ta = 0, tw = 0, tn = 0, tm = 3.4e38f;
#pragma unroll
        for (int i = 0; i < 16; i++) {
            ta += ra[i]; tw += rw[i]; tn += rn[i]; tm = fminf(tm, rm[i]);
        }
        const float inv = 1.0f / (float)N;
        const float alignment = ta * inv;
        const float weighted  = tw * inv;
        const float neg       = tn * inv;
        const float contrast  = alignment - neg;
        const float margin    = fmaxf(contrast - 0.2f, 0.0f);
        const float overall   = 0.7f * weighted + 0.3f * contrast;
        out[0] = alignment;
        out[1] = weighted;
        float* p = out + 2 + NM;
        p[0] = contrast;
        p[1] = margin;
        p[2] = alignment;   // positive_alignment
        p[3] = neg;
        p[4 + N] = tm;      // min_step_coherence
        p[5 + N] = overall;
    }
}

// ---------------------------------------------------------------------------
extern "C" void kernel_launch(void* const* d_in, const int* in_sizes, int n_in,
                              void* d_out, int out_size, void* d_ws, size_t ws_size,
                              hipStream_t stream) {
    const float* step  = (const float*)d_in[0];
    const float* modal = (const float*)d_in[1];
    const float* negs  = (const float*)d_in[2];
    float* out = (float*)d_out;

    const int K = 1024;
    const int N = in_sizes[0] / K;   // 8192
    const int M = in_sizes[1] / K;   // 4096
    const size_t NM = (size_t)N * (size_t)M;

    float* ina        = (float*)d_ws;          // N
    float* inb        = ina + N;               // M
    float* inn        = inb + M;               // M
    unsigned* negmax  = (unsigned*)(inn + M);  // N
    float* wsum       = (float*)(negmax + N);  // N

    char* arena    = (char*)d_out + 16;
    float* attn    = out + 2;
    float* perstep = out + 2 + NM + 4;

    // 1. convert inputs to bf16 chunks + inverse norms + init atomics
    convert_norms_kernel<<<(N + 2 * M) / 4, 256, 0, stream>>>(
        step, modal, negs, arena, ina, inb, inn, negmax, N, M);

    // 2. fused GEMM (L2-resident supertile mapping)
    const int nblocks = (N / 128) * ((2 * M) / 128);
    gemm_fused_kernel<<<nblocks, 256, 0, stream>>>(arena, N, M, inn, negmax);

    // 3. softmax + exact fp32 fix-up, writes fp32 attention + per-row outs
    softmax_fix_kernel<<<N, 256, 0, stream>>>(arena, step, modal, ina, inb,
                                              perstep, wsum, attn);

    // 4. scalars
    finalize_kernel<<<1, 1024, 0, stream>>>(perstep, wsum, negmax, ina, out, N, NM);
}